// Round 4
// baseline (11.049 us; speedup 1.0000x reference)
//
#include <hip/hip_runtime.h>

#define G0 64
#define G1 64
#define HH 512
#define WW 512
#define CC 8
#define NBLOCKS 2048
#define NXCD 8

typedef float f32x4 __attribute__((ext_vector_type(4)));

// One thread per half-pixel (float4 of 4 channels). 524288 threads total.
// XCD-aware block swizzle: 256 consecutive blocks (= 8 whole batches) per XCD,
// so each batch's image lines live in exactly one XCD's L2 (no cross-XCD dup).
__global__ __launch_bounds__(256) void ImageInterpolator_kernel(
    const float* __restrict__ image,
    const float* __restrict__ section,
    float* __restrict__ out)
{
    // bijective swizzle: nwg = 2048, 8 XCDs, 256 chunks per XCD
    const int bid = (int)blockIdx.x;
    const int wg  = (bid & (NXCD - 1)) * (NBLOCKS / NXCD) + (bid >> 3);

    const int idx = wg * 256 + threadIdx.x;            // 0 .. 64*64*64*2-1
    const int h  = idx & 1;                            // channel half
    const int g1 = (idx >> 1) & 63;
    const int g0 = (idx >> 7) & 63;
    const int b  = wg >> 5;                            // 32 blocks per batch (block-uniform)

    const float s0 = section[b * 3 + 0];
    const float s1 = section[b * 3 + 1];
    const float sz = section[b * 3 + 2];

    const float step = 1.0f / 63.0f;                   // linspace(0,1,64) step
    const float q0 = s0 + ((float)g0 * step) * sz;
    const float q1 = s1 + ((float)g1 * step) * sz;

    const float i0 = fminf(fmaxf(q0 * 511.0f, 0.0f), 511.0f);
    const float i1 = fminf(fmaxf(q1 * 511.0f, 0.0f), 511.0f);
    const float f0 = floorf(i0);
    const float f1 = floorf(i1);
    const float w0 = i0 - f0;
    const float w1 = i1 - f1;

    const int lo0 = (int)f0;
    const int lo1 = (int)f1;
    const int hi0 = min(lo0 + 1, HH - 1);
    const int hi1 = min(lo1 + 1, WW - 1);

    const float* base = image + (size_t)b * HH * WW * CC + (h << 2);
    const f32x4 v00 = *(const f32x4*)(base + ((size_t)lo0 * WW + lo1) * CC);
    const f32x4 v01 = *(const f32x4*)(base + ((size_t)lo0 * WW + hi1) * CC);
    const f32x4 v10 = *(const f32x4*)(base + ((size_t)hi0 * WW + lo1) * CC);
    const f32x4 v11 = *(const f32x4*)(base + ((size_t)hi0 * WW + hi1) * CC);

    const float om0 = 1.0f - w0;
    const float om1 = 1.0f - w1;

    const f32x4 r = (v00 * om1 + v01 * w1) * om0 + (v10 * om1 + v11 * w1) * w0;

    // nontemporal store: don't let the 8.4 MB output evict image lines from L2
    __builtin_nontemporal_store(r, (f32x4*)(out + (size_t)idx * 4));
}

extern "C" void kernel_launch(void* const* d_in, const int* in_sizes, int n_in,
                              void* d_out, int out_size, void* d_ws, size_t ws_size,
                              hipStream_t stream) {
    const float* image   = (const float*)d_in[0];
    const float* section = (const float*)d_in[1];
    float* out = (float*)d_out;

    ImageInterpolator_kernel<<<NBLOCKS, 256, 0, stream>>>(image, section, out);
}